// Round 12
// baseline (76.814 us; speedup 1.0000x reference)
//
#include <hip/hip_runtime.h>
#include <hip/hip_bf16.h>
#include <math.h>

#define BB 8
#define SS 64
#define NN 256
#define ST 128
#define IF 64
#define OF 64
#define H1 32
#define ALPHA 0.2f
#define LOG2E 1.4426950408889634f

typedef short short8 __attribute__((ext_vector_type(8)));
typedef short short4_t __attribute__((ext_vector_type(4)));
typedef float f32x4 __attribute__((ext_vector_type(4)));
typedef unsigned short ushort_t;

static __device__ __forceinline__ ushort_t f2bf(float f) {
    __hip_bfloat16 h = __float2bfloat16(f);
    return *reinterpret_cast<ushort_t*>(&h);
}

// ---- Kernel 1 (fused): stage-1 MLPs + Aa + W-gen. Block = 2 bs, 512 thr ----
__global__ __launch_bounds__(512) void k_hyper2(
    const float* __restrict__ hyper,
    const float* __restrict__ w1, const float* __restrict__ b1,
    const float* __restrict__ w2, const float* __restrict__ b2,
    const float* __restrict__ aw1, const float* __restrict__ ab1,
    const float* __restrict__ aw2, const float* __restrict__ ab2,
    float* __restrict__ Wd, float* __restrict__ Aa)
{
    const int t = threadIdx.x;
    const int bs0 = blockIdx.x * 2;
    __shared__ float hy[2][ST];
    __shared__ float hdn_s[2][H1];
    __shared__ float hda_s[2][H1];
    if (t < 2 * ST)
        hy[t >> 7][t & 127] = hyper[(size_t)bs0 * ST + t];
    __syncthreads();
    if (t < 64) {
        const int q = t >> 5, c = t & 31;
        float acc = b1[c];
#pragma unroll 4
        for (int k = 0; k < ST; ++k) acc = fmaf(hy[q][k], w1[k * H1 + c], acc);
        hdn_s[q][c] = fmaxf(acc, 0.f);
    } else if (t < 128) {
        const int tt = t - 64;
        const int q = tt >> 5, c = tt & 31;
        float acc = ab1[c];
#pragma unroll 4
        for (int k = 0; k < ST; ++k) acc = fmaf(hy[q][k], aw1[k * H1 + c], acc);
        hda_s[q][c] = fmaxf(acc, 0.f);
    }
    __syncthreads();
    if (t < 256) {
        const int q = t >> 7, c = t & 127;
        float a = ab2[c];
#pragma unroll
        for (int k = 0; k < H1; ++k)
            a = fmaf(hda_s[q][k], aw2[k * 128 + c], a);
        Aa[(size_t)(bs0 + q) * 128 + c] = fabsf(a);
    }
#pragma unroll
    for (int p = 0; p < 2; ++p) {
        const int e = t * 4 + p * 2048;
        const float4 bb = *(const float4*)&b2[e];
        float4 a0 = bb, a1 = bb;
#pragma unroll
        for (int kq = 0; kq < 8; ++kq) {
            const float4 h0 = *(const float4*)&hdn_s[0][kq * 4];
            const float4 h1 = *(const float4*)&hdn_s[1][kq * 4];
#pragma unroll
            for (int c = 0; c < 4; ++c) {
                const float4 wv = *(const float4*)&w2[(size_t)(kq * 4 + c) * 4096 + e];
                const float s0 = (c == 0) ? h0.x : (c == 1) ? h0.y : (c == 2) ? h0.z : h0.w;
                const float s1 = (c == 0) ? h1.x : (c == 1) ? h1.y : (c == 2) ? h1.z : h1.w;
                a0.x = fmaf(s0, wv.x, a0.x); a0.y = fmaf(s0, wv.y, a0.y);
                a0.z = fmaf(s0, wv.z, a0.z); a0.w = fmaf(s0, wv.w, a0.w);
                a1.x = fmaf(s1, wv.x, a1.x); a1.y = fmaf(s1, wv.y, a1.y);
                a1.z = fmaf(s1, wv.z, a1.z); a1.w = fmaf(s1, wv.w, a1.w);
            }
        }
        a0.x = fabsf(a0.x); a0.y = fabsf(a0.y); a0.z = fabsf(a0.z); a0.w = fabsf(a0.w);
        a1.x = fabsf(a1.x); a1.y = fabsf(a1.y); a1.z = fabsf(a1.z); a1.w = fabsf(a1.w);
        *(float4*)&Wd[(size_t)(bs0 + 0) * 4096 + e] = a0;
        *(float4*)&Wd[(size_t)(bs0 + 1) * 4096 + e] = a1;
    }
}

// ------- Kernel 2: per (b,s): h = x@W via bf16 MFMA; exact-f32 e1/e2 ---------
__global__ __launch_bounds__(256) void k_h(
    const float* __restrict__ x, const float* __restrict__ Wd,
    const float* __restrict__ Aa,
    ushort_t* __restrict__ HbTw, float* __restrict__ E1, float* __restrict__ E2)
{
    const int bs = blockIdx.x;
    const int tid = threadIdx.x;
    const int wid = tid >> 6;
    const int lane = tid & 63;
    const int l15 = lane & 15;
    const int lhi = lane >> 4;

    __shared__ char xl[NN * IF * 4];   // 64 KB f32 x-slice, byte ^= (row&7)<<5
    __shared__ ushort_t Wt[IF * OF];   // 8 KB  W^T [o][k] bf16, XOR-swizzled
    __shared__ float wa1s[IF], wa2s[IF];
    __shared__ float a1s[OF], a2s[OF];

    if (tid < 64) a1s[tid] = Aa[(size_t)bs * 128 + tid];
    else if (tid < 128) a2s[tid - 64] = Aa[(size_t)bs * 128 + tid];

    {
        const float4* x4 = (const float4*)(x + (size_t)bs * NN * IF);
#pragma unroll
        for (int p = 0; p < 16; ++p) {
            const int idx = tid + p * 256;
            const int row = idx >> 4;
            const int byte = (row << 8) | ((((idx & 15) << 4)) ^ ((row & 7) << 5));
            *(float4*)(xl + byte) = x4[idx];
        }
    }
    {
        const float4* w4 = (const float4*)(Wd + (size_t)bs * 4096);
#pragma unroll
        for (int p = 0; p < 4; ++p) {
            const int idx = tid + p * 256;
            const float4 f = w4[idx];
            const int k = (idx * 4) >> 6;
            const int o0 = (idx * 4) & 63;
            Wt[(o0 + 0) * 64 + (k ^ (((o0 + 0) & 7) << 3))] = f2bf(f.x);
            Wt[(o0 + 1) * 64 + (k ^ (((o0 + 1) & 7) << 3))] = f2bf(f.y);
            Wt[(o0 + 2) * 64 + (k ^ (((o0 + 2) & 7) << 3))] = f2bf(f.z);
            Wt[(o0 + 3) * 64 + (k ^ (((o0 + 3) & 7) << 3))] = f2bf(f.w);
        }
    }
    __syncthreads();

    if (tid < 64) {
        const float4* wr = (const float4*)(Wd + (size_t)bs * 4096 + tid * 64);
        float s1 = 0.f, s2 = 0.f;
#pragma unroll
        for (int q = 0; q < 16; ++q) {
            const float4 f = wr[q];
            const float4 u = *(const float4*)&a1s[q * 4];
            const float4 v = *(const float4*)&a2s[q * 4];
            s1 += f.x * u.x + f.y * u.y + f.z * u.z + f.w * u.w;
            s2 += f.x * v.x + f.y * v.y + f.z * v.z + f.w * v.w;
        }
        wa1s[tid] = s1; wa2s[tid] = s2;
    }
    __syncthreads();

    {
        float s1 = 0.f, s2 = 0.f;
        const int rbase = tid << 8;
        const int sw = (tid & 7) << 5;
#pragma unroll
        for (int q = 0; q < 16; ++q) {
            const float4 f = *(const float4*)(xl + (rbase | ((q << 4) ^ sw)));
            const float4 u = *(const float4*)&wa1s[q * 4];
            const float4 v = *(const float4*)&wa2s[q * 4];
            s1 += f.x * u.x + f.y * u.y + f.z * u.z + f.w * u.w;
            s2 += f.x * v.x + f.y * v.y + f.z * v.z + f.w * v.w;
        }
        E1[(size_t)bs * NN + tid] = s1 * LOG2E;
        E2[(size_t)bs * NN + tid] = s2 * LOG2E;
    }

    f32x4 acc[4][4];
#pragma unroll
    for (int mt = 0; mt < 4; ++mt)
#pragma unroll
        for (int nt = 0; nt < 4; ++nt) acc[mt][nt] = (f32x4){0.f, 0.f, 0.f, 0.f};

    short8 af[4][2];
#pragma unroll
    for (int mt = 0; mt < 4; ++mt) {
        const int row = wid * 64 + mt * 16 + l15;
        const int rb = row << 8;
        const int sw = (row & 7) << 5;
#pragma unroll
        for (int ks = 0; ks < 2; ++ks) {
            const int kb = (ks * 32 + lhi * 8) * 4;
            const float4 fa = *(const float4*)(xl + (rb | (kb ^ sw)));
            const float4 fb = *(const float4*)(xl + (rb | ((kb + 16) ^ sw)));
            short8 pk;
            pk[0] = (short)f2bf(fa.x); pk[1] = (short)f2bf(fa.y);
            pk[2] = (short)f2bf(fa.z); pk[3] = (short)f2bf(fa.w);
            pk[4] = (short)f2bf(fb.x); pk[5] = (short)f2bf(fb.y);
            pk[6] = (short)f2bf(fb.z); pk[7] = (short)f2bf(fb.w);
            af[mt][ks] = pk;
        }
    }
    short8 bfr[4][2];
#pragma unroll
    for (int nt = 0; nt < 4; ++nt) {
        const int o = nt * 16 + l15;
#pragma unroll
        for (int ks = 0; ks < 2; ++ks) {
            const int k0 = ks * 32 + lhi * 8;
            bfr[nt][ks] = *(const short8*)&Wt[o * 64 + (k0 ^ ((o & 7) << 3))];
        }
    }
#pragma unroll
    for (int mt = 0; mt < 4; ++mt)
#pragma unroll
        for (int nt = 0; nt < 4; ++nt) {
            acc[mt][nt] = __builtin_amdgcn_mfma_f32_16x16x32_bf16(
                af[mt][0], bfr[nt][0], acc[mt][nt], 0, 0, 0);
            acc[mt][nt] = __builtin_amdgcn_mfma_f32_16x16x32_bf16(
                af[mt][1], bfr[nt][1], acc[mt][nt], 0, 0, 0);
        }

    ushort_t* hbw = HbTw + (size_t)bs * (OF * NN);
#pragma unroll
    for (int mt = 0; mt < 4; ++mt) {
        const int nb = wid * 8 + mt * 2 + (lhi >> 1);
        const int ne = (lhi & 1) * 4;
#pragma unroll
        for (int nt = 0; nt < 4; ++nt) {
            short4_t pk;
            pk[0] = (short)f2bf(acc[mt][nt][0]);
            pk[1] = (short)f2bf(acc[mt][nt][1]);
            pk[2] = (short)f2bf(acc[mt][nt][2]);
            pk[3] = (short)f2bf(acc[mt][nt][3]);
            *(short4_t*)(hbw + ((size_t)(nt * 32 + nb) * 16 + l15) * 8 + ne) = pk;
        }
    }
}

// ------ Kernel 3a: softmax-over-s stats, PACKED bf16 (M',R) ------------------
__global__ __launch_bounds__(256) void k_softstats(
    const float* __restrict__ E1, const float* __restrict__ E2,
    const int* __restrict__ Adj, unsigned int* __restrict__ MRw)
{
    const int b = blockIdx.x & 7;
    const int i0 = (blockIdx.x >> 3) * 4;
    const int t = threadIdx.x;         // j
    __shared__ float e1s[4][SS];
    {
        const int ii = t >> 6, s = t & 63;
        e1s[ii][s] = E1[(size_t)(b * SS + s) * NN + i0 + ii];
    }
    float e2r[SS];
#pragma unroll
    for (int s = 0; s < SS; ++s)
        e2r[s] = E2[(size_t)(b * SS + s) * NN + t];
    __syncthreads();

#pragma unroll
    for (int ii = 0; ii < 4; ++ii) {
        float v[SS];
        float mx = -3.0e38f;
#pragma unroll
        for (int s = 0; s < SS; ++s) {
            float u = e1s[ii][s] + e2r[s];
            u = fmaxf(u, ALPHA * u);
            v[s] = u;
            mx = fmaxf(mx, u);
        }
        const unsigned int mu = (unsigned int)f2bf(mx);
        const float mUse = __uint_as_float(mu << 16);
        float sum = 0.f;
#pragma unroll
        for (int s = 0; s < SS; ++s)
            sum += exp2f(v[s] - mUse);
        const int i = i0 + ii;
        const int adj = Adj[(size_t)i * NN + t];
        const float r = (adj > 0) ? (1.f / sum) : -0.015625f;
        MRw[((((size_t)b * 16 + (i >> 4)) * 32 + (t >> 3)) * 16 + (i & 15)) * 8
            + (t & 7)] = (mu << 16) | (unsigned int)f2bf(r);
    }
}

// ------ Kernel 3b: O = ELU(A @ H) via bf16 MFMA. Block = 64 rows x 2 s. ------
// Wave = 16 rows (one row-group). The MR stats stream is s-invariant and is
// loaded ONCE per wave for both s values -> MR traffic/requests halve.
// Grid = 8 b (XCD-pinned) x 32 s-pairs x 4 row-quarters = 1024 blocks.
__global__ __launch_bounds__(256, 4) void k_attn(
    const ushort_t* __restrict__ HbTw, const float* __restrict__ E1,
    const float* __restrict__ E2, const unsigned int* __restrict__ MRw,
    float* __restrict__ out)
{
    const int b = blockIdx.x & 7;            // XCD-pinned batch
    const int q = blockIdx.x >> 3;           // 0..127
    const int s0 = (q >> 2) * 2;             // s-pair base
    const int quarter = q & 3;
    const int bs0 = b * 64 + s0;
    const int tid = threadIdx.x;
    const int wid = tid >> 6;                // wave 0..3
    const int lane = tid & 63;
    const int l15 = lane & 15;
    const int lhi = lane >> 4;
    const int rb0 = quarter * 64 + wid * 16; // this wave's 16 rows
    const int rg = rb0 >> 4;                 // row-group 0..15

    __shared__ float e2s[2][NN];
    e2s[0][tid] = E2[(size_t)bs0 * NN + tid];
    e2s[1][tid] = E2[(size_t)(bs0 + 1) * NN + tid];
    __syncthreads();

    float e1r[2];
    e1r[0] = E1[(size_t)bs0 * NN + rb0 + l15];
    e1r[1] = E1[(size_t)(bs0 + 1) * NN + rb0 + l15];

    f32x4 acc[2][4];                         // [s][nt]
#pragma unroll
    for (int sp = 0; sp < 2; ++sp)
#pragma unroll
        for (int nt = 0; nt < 4; ++nt) acc[sp][nt] = (f32x4){0.f, 0.f, 0.f, 0.f};

    const ushort_t* hbw0 = HbTw + (size_t)bs0 * (OF * NN);
    const ushort_t* hbw1 = hbw0 + OF * NN;
    const unsigned int* mr = MRw + (size_t)b * (NN * NN)
                           + ((size_t)rg * 32) * 128 + l15 * 8;

    for (int ch = 0; ch < 4; ++ch) {
#pragma unroll
        for (int ks = 0; ks < 2; ++ks) {
            const int kb = ch * 8 + ks * 4 + lhi;   // j/8 block index
            // B fragments for both s (contiguous 16B/lane)
            short8 bfr[2][4];
#pragma unroll
            for (int nt = 0; nt < 4; ++nt) {
                const size_t off = ((size_t)(nt * 32 + kb) * 16 + l15) * 8;
                bfr[0][nt] = *(const short8*)(hbw0 + off);
                bfr[1][nt] = *(const short8*)(hbw1 + off);
            }
            // MR stats: ONE stream shared by both s (contiguous 32B/lane)
            const uint4 m0 = *(const uint4*)(mr + kb * 128);
            const uint4 m1 = *(const uint4*)(mr + kb * 128 + 4);
            const unsigned int wv[8] = {m0.x, m0.y, m0.z, m0.w,
                                        m1.x, m1.y, m1.z, m1.w};
            const int k0 = ch * 64 + ks * 32 + lhi * 8;
            // per-s: e2 slice, A fragment, 4 MFMAs
#pragma unroll
            for (int sp = 0; sp < 2; ++sp) {
                const float4 lo = *(const float4*)&e2s[sp][k0];
                const float4 hi = *(const float4*)&e2s[sp][k0 + 4];
                const float e2v[8] = {lo.x, lo.y, lo.z, lo.w,
                                      hi.x, hi.y, hi.z, hi.w};
                const float e1v = e1r[sp];
                short8 pk;
#pragma unroll
                for (int kk = 0; kk < 8; ++kk) {
                    const float Mf = __uint_as_float(wv[kk] & 0xFFFF0000u);
                    const float Rf = __uint_as_float(wv[kk] << 16);
                    float v = e1v + e2v[kk];
                    v = fmaxf(v, ALPHA * v);
                    const float a = (Rf < 0.f) ? -Rf : exp2f(v - Mf) * Rf;
                    pk[kk] = (short)f2bf(a);
                }
#pragma unroll
                for (int nt = 0; nt < 4; ++nt)
                    acc[sp][nt] = __builtin_amdgcn_mfma_f32_16x16x32_bf16(
                        pk, bfr[sp][nt], acc[sp][nt], 0, 0, 0);
            }
        }
    }

    // ---- epilogue: ELU + store f32 (both s)
#pragma unroll
    for (int sp = 0; sp < 2; ++sp) {
        float* ob = out + (size_t)(bs0 + sp) * (NN * OF);
        const int rbase = rb0 + lhi * 4;
#pragma unroll
        for (int nt = 0; nt < 4; ++nt) {
            const int o = nt * 16 + l15;
#pragma unroll
            for (int reg = 0; reg < 4; ++reg) {
                float v = acc[sp][nt][reg];
                v = (v > 0.f) ? v : (__expf(v) - 1.f);
                ob[(size_t)(rbase + reg) * OF + o] = v;
            }
        }
    }
}

extern "C" void kernel_launch(void* const* d_in, const int* in_sizes, int n_in,
                              void* d_out, int out_size, void* d_ws, size_t ws_size,
                              hipStream_t stream)
{
    const float* hyper = (const float*)d_in[0];
    const float* x     = (const float*)d_in[1];
    const int*   Adj   = (const int*)d_in[2];
    const float* w1    = (const float*)d_in[3];
    const float* b1    = (const float*)d_in[4];
    const float* w2    = (const float*)d_in[5];
    const float* b2    = (const float*)d_in[6];
    const float* aw1   = (const float*)d_in[7];
    const float* ab1   = (const float*)d_in[8];
    const float* aw2   = (const float*)d_in[9];
    const float* ab2   = (const float*)d_in[10];
    float* out = (float*)d_out;

    float* ws      = (float*)d_ws;
    float* Wd      = ws;                      // 512*4096
    float* Aa      = Wd + 2097152;            // 512*128
    ushort_t* HbTw = (ushort_t*)(Aa + 65536); // 512*64*256 bf16, fragment-native
    float* E1      = (float*)(HbTw + 8388608);// 512*256 (log2e-scaled)
    float* E2      = E1 + 131072;             // 512*256 (log2e-scaled)
    unsigned int* MRw = (unsigned int*)(E2 + 131072); // 8*256*256, fragment-native

    k_hyper2<<<dim3(256), dim3(512), 0, stream>>>(hyper, w1, b1, w2, b2,
                                                  aw1, ab1, aw2, ab2, Wd, Aa);
    k_h<<<dim3(512), dim3(256), 0, stream>>>(x, Wd, Aa, HbTw, E1, E2);
    k_softstats<<<dim3(512), dim3(256), 0, stream>>>(E1, E2, Adj, MRw);
    k_attn<<<dim3(1024), dim3(256), 0, stream>>>(HbTw, E1, E2, MRw, out);
}

// Round 13
// 73.032 us; speedup vs baseline: 1.0518x; 1.0518x over previous
//
#include <hip/hip_runtime.h>
#include <hip/hip_bf16.h>
#include <math.h>

#define BB 8
#define SS 64
#define NN 256
#define ST 128
#define IF 64
#define OF 64
#define H1 32
#define ALPHA 0.2f
#define LOG2E 1.4426950408889634f

typedef short short8 __attribute__((ext_vector_type(8)));
typedef short short4_t __attribute__((ext_vector_type(4)));
typedef float f32x4 __attribute__((ext_vector_type(4)));
typedef unsigned short ushort_t;

static __device__ __forceinline__ ushort_t f2bf(float f) {
    __hip_bfloat16 h = __float2bfloat16(f);
    return *reinterpret_cast<ushort_t*>(&h);
}

// ---- Kernel 1 (fused): stage-1 MLPs + Aa + W-gen. Block = 2 bs, 512 thr ----
__global__ __launch_bounds__(512) void k_hyper2(
    const float* __restrict__ hyper,
    const float* __restrict__ w1, const float* __restrict__ b1,
    const float* __restrict__ w2, const float* __restrict__ b2,
    const float* __restrict__ aw1, const float* __restrict__ ab1,
    const float* __restrict__ aw2, const float* __restrict__ ab2,
    float* __restrict__ Wd, float* __restrict__ Aa)
{
    const int t = threadIdx.x;
    const int bs0 = blockIdx.x * 2;
    __shared__ float hy[2][ST];
    __shared__ float hdn_s[2][H1];
    __shared__ float hda_s[2][H1];
    if (t < 2 * ST)
        hy[t >> 7][t & 127] = hyper[(size_t)bs0 * ST + t];
    __syncthreads();
    if (t < 64) {
        const int q = t >> 5, c = t & 31;
        float acc = b1[c];
#pragma unroll 4
        for (int k = 0; k < ST; ++k) acc = fmaf(hy[q][k], w1[k * H1 + c], acc);
        hdn_s[q][c] = fmaxf(acc, 0.f);
    } else if (t < 128) {
        const int tt = t - 64;
        const int q = tt >> 5, c = tt & 31;
        float acc = ab1[c];
#pragma unroll 4
        for (int k = 0; k < ST; ++k) acc = fmaf(hy[q][k], aw1[k * H1 + c], acc);
        hda_s[q][c] = fmaxf(acc, 0.f);
    }
    __syncthreads();
    if (t < 256) {
        const int q = t >> 7, c = t & 127;
        float a = ab2[c];
#pragma unroll
        for (int k = 0; k < H1; ++k)
            a = fmaf(hda_s[q][k], aw2[k * 128 + c], a);
        Aa[(size_t)(bs0 + q) * 128 + c] = fabsf(a);
    }
#pragma unroll
    for (int p = 0; p < 2; ++p) {
        const int e = t * 4 + p * 2048;
        const float4 bb = *(const float4*)&b2[e];
        float4 a0 = bb, a1 = bb;
#pragma unroll
        for (int kq = 0; kq < 8; ++kq) {
            const float4 h0 = *(const float4*)&hdn_s[0][kq * 4];
            const float4 h1 = *(const float4*)&hdn_s[1][kq * 4];
#pragma unroll
            for (int c = 0; c < 4; ++c) {
                const float4 wv = *(const float4*)&w2[(size_t)(kq * 4 + c) * 4096 + e];
                const float s0 = (c == 0) ? h0.x : (c == 1) ? h0.y : (c == 2) ? h0.z : h0.w;
                const float s1 = (c == 0) ? h1.x : (c == 1) ? h1.y : (c == 2) ? h1.z : h1.w;
                a0.x = fmaf(s0, wv.x, a0.x); a0.y = fmaf(s0, wv.y, a0.y);
                a0.z = fmaf(s0, wv.z, a0.z); a0.w = fmaf(s0, wv.w, a0.w);
                a1.x = fmaf(s1, wv.x, a1.x); a1.y = fmaf(s1, wv.y, a1.y);
                a1.z = fmaf(s1, wv.z, a1.z); a1.w = fmaf(s1, wv.w, a1.w);
            }
        }
        a0.x = fabsf(a0.x); a0.y = fabsf(a0.y); a0.z = fabsf(a0.z); a0.w = fabsf(a0.w);
        a1.x = fabsf(a1.x); a1.y = fabsf(a1.y); a1.z = fabsf(a1.z); a1.w = fabsf(a1.w);
        *(float4*)&Wd[(size_t)(bs0 + 0) * 4096 + e] = a0;
        *(float4*)&Wd[(size_t)(bs0 + 1) * 4096 + e] = a1;
    }
}

// ------- Kernel 2: per (b,s): h = x@W via bf16 MFMA; exact-f32 e1/e2 ---------
// x slice staged ONCE, coalesced, into XOR-swizzled f32 LDS; fragments and
// e-dots read from LDS (kills the strided global gathers).
__global__ __launch_bounds__(256) void k_h(
    const float* __restrict__ x, const float* __restrict__ Wd,
    const float* __restrict__ Aa,
    ushort_t* __restrict__ HbTw, float* __restrict__ E1, float* __restrict__ E2)
{
    const int bs = blockIdx.x;
    const int tid = threadIdx.x;
    const int wid = tid >> 6;
    const int lane = tid & 63;
    const int l15 = lane & 15;
    const int lhi = lane >> 4;

    __shared__ char xl[NN * IF * 4];   // 64 KB f32 x-slice, byte ^= (row&7)<<5
    __shared__ ushort_t Wt[IF * OF];   // 8 KB  W^T [o][k] bf16, XOR-swizzled
    __shared__ float wa1s[IF], wa2s[IF];
    __shared__ float a1s[OF], a2s[OF];

    if (tid < 64) a1s[tid] = Aa[(size_t)bs * 128 + tid];
    else if (tid < 128) a2s[tid - 64] = Aa[(size_t)bs * 128 + tid];

    // stage x (coalesced float4), swizzled
    {
        const float4* x4 = (const float4*)(x + (size_t)bs * NN * IF);
#pragma unroll
        for (int p = 0; p < 16; ++p) {
            const int idx = tid + p * 256;          // float4 units, 4096 total
            const int row = idx >> 4;
            const int byte = (row << 8) | ((((idx & 15) << 4)) ^ ((row & 7) << 5));
            *(float4*)(xl + byte) = x4[idx];
        }
    }
    // transpose W (f32 [k][o]) -> bf16 Wt[o][k ^ ((o&7)<<3)]
    {
        const float4* w4 = (const float4*)(Wd + (size_t)bs * 4096);
#pragma unroll
        for (int p = 0; p < 4; ++p) {
            const int idx = tid + p * 256;
            const float4 f = w4[idx];
            const int k = (idx * 4) >> 6;
            const int o0 = (idx * 4) & 63;
            Wt[(o0 + 0) * 64 + (k ^ (((o0 + 0) & 7) << 3))] = f2bf(f.x);
            Wt[(o0 + 1) * 64 + (k ^ (((o0 + 1) & 7) << 3))] = f2bf(f.y);
            Wt[(o0 + 2) * 64 + (k ^ (((o0 + 2) & 7) << 3))] = f2bf(f.z);
            Wt[(o0 + 3) * 64 + (k ^ (((o0 + 3) & 7) << 3))] = f2bf(f.w);
        }
    }
    __syncthreads();

    // wa1/wa2 = W @ a1, W @ a2 (exact f32; threads 0..63, one k-row each)
    if (tid < 64) {
        const float4* wr = (const float4*)(Wd + (size_t)bs * 4096 + tid * 64);
        float s1 = 0.f, s2 = 0.f;
#pragma unroll
        for (int q = 0; q < 16; ++q) {
            const float4 f = wr[q];
            const float4 u = *(const float4*)&a1s[q * 4];
            const float4 v = *(const float4*)&a2s[q * 4];
            s1 += f.x * u.x + f.y * u.y + f.z * u.z + f.w * u.w;
            s2 += f.x * v.x + f.y * v.y + f.z * v.z + f.w * v.w;
        }
        wa1s[tid] = s1; wa2s[tid] = s2;
    }
    __syncthreads();

    // e1/e2: exact f32 row dot from LDS (row = tid), pre-scaled by log2e
    {
        float s1 = 0.f, s2 = 0.f;
        const int rbase = tid << 8;
        const int sw = (tid & 7) << 5;
#pragma unroll
        for (int q = 0; q < 16; ++q) {
            const float4 f = *(const float4*)(xl + (rbase | ((q << 4) ^ sw)));
            const float4 u = *(const float4*)&wa1s[q * 4];
            const float4 v = *(const float4*)&wa2s[q * 4];
            s1 += f.x * u.x + f.y * u.y + f.z * u.z + f.w * u.w;
            s2 += f.x * v.x + f.y * v.y + f.z * v.z + f.w * v.w;
        }
        E1[(size_t)bs * NN + tid] = s1 * LOG2E;
        E2[(size_t)bs * NN + tid] = s2 * LOG2E;
    }

    // ---- MFMA: h = x(256x64) @ W(64x64); wave owns rows wid*64..+63
    f32x4 acc[4][4];
#pragma unroll
    for (int mt = 0; mt < 4; ++mt)
#pragma unroll
        for (int nt = 0; nt < 4; ++nt) acc[mt][nt] = (f32x4){0.f, 0.f, 0.f, 0.f};

    short8 af[4][2];
#pragma unroll
    for (int mt = 0; mt < 4; ++mt) {
        const int row = wid * 64 + mt * 16 + l15;
        const int rb = row << 8;
        const int sw = (row & 7) << 5;
#pragma unroll
        for (int ks = 0; ks < 2; ++ks) {
            const int kb = (ks * 32 + lhi * 8) * 4;   // byte offset of k0 (32B-aligned)
            const float4 fa = *(const float4*)(xl + (rb | (kb ^ sw)));
            const float4 fb = *(const float4*)(xl + (rb | ((kb + 16) ^ sw)));
            short8 pk;
            pk[0] = (short)f2bf(fa.x); pk[1] = (short)f2bf(fa.y);
            pk[2] = (short)f2bf(fa.z); pk[3] = (short)f2bf(fa.w);
            pk[4] = (short)f2bf(fb.x); pk[5] = (short)f2bf(fb.y);
            pk[6] = (short)f2bf(fb.z); pk[7] = (short)f2bf(fb.w);
            af[mt][ks] = pk;
        }
    }
    short8 bfr[4][2];
#pragma unroll
    for (int nt = 0; nt < 4; ++nt) {
        const int o = nt * 16 + l15;
#pragma unroll
        for (int ks = 0; ks < 2; ++ks) {
            const int k0 = ks * 32 + lhi * 8;
            bfr[nt][ks] = *(const short8*)&Wt[o * 64 + (k0 ^ ((o & 7) << 3))];
        }
    }
#pragma unroll
    for (int mt = 0; mt < 4; ++mt)
#pragma unroll
        for (int nt = 0; nt < 4; ++nt) {
            acc[mt][nt] = __builtin_amdgcn_mfma_f32_16x16x32_bf16(
                af[mt][0], bfr[nt][0], acc[mt][nt], 0, 0, 0);
            acc[mt][nt] = __builtin_amdgcn_mfma_f32_16x16x32_bf16(
                af[mt][1], bfr[nt][1], acc[mt][nt], 0, 0, 0);
        }

    // epilogue -> HbTw[o/16][n/8][o%16][n%8]: 8B store per (mt,nt)
    ushort_t* hbw = HbTw + (size_t)bs * (OF * NN);
#pragma unroll
    for (int mt = 0; mt < 4; ++mt) {
        const int nb = wid * 8 + mt * 2 + (lhi >> 1);
        const int ne = (lhi & 1) * 4;
#pragma unroll
        for (int nt = 0; nt < 4; ++nt) {
            short4_t pk;
            pk[0] = (short)f2bf(acc[mt][nt][0]);
            pk[1] = (short)f2bf(acc[mt][nt][1]);
            pk[2] = (short)f2bf(acc[mt][nt][2]);
            pk[3] = (short)f2bf(acc[mt][nt][3]);
            *(short4_t*)(hbw + ((size_t)(nt * 32 + nb) * 16 + l15) * 8 + ne) = pk;
        }
    }
}

// ------ Kernel 3a: softmax-over-s stats, PACKED bf16 (M',R) ------------------
// Fragment-native MRw[b][i/16][j/8][i%16][j%8]. XCD-pinned: b = blockIdx%8,
// so batch b's MR is produced on XCD b (and consumed there by k_attn).
__global__ __launch_bounds__(256) void k_softstats(
    const float* __restrict__ E1, const float* __restrict__ E2,
    const int* __restrict__ Adj, unsigned int* __restrict__ MRw)
{
    const int b = blockIdx.x & 7;
    const int i0 = (blockIdx.x >> 3) * 4;
    const int t = threadIdx.x;         // j
    __shared__ float e1s[4][SS];
    {
        const int ii = t >> 6, s = t & 63;
        e1s[ii][s] = E1[(size_t)(b * SS + s) * NN + i0 + ii];
    }
    float e2r[SS];
#pragma unroll
    for (int s = 0; s < SS; ++s)
        e2r[s] = E2[(size_t)(b * SS + s) * NN + t];
    __syncthreads();

#pragma unroll
    for (int ii = 0; ii < 4; ++ii) {
        float v[SS];
        float mx = -3.0e38f;
#pragma unroll
        for (int s = 0; s < SS; ++s) {
            float u = e1s[ii][s] + e2r[s];
            u = fmaxf(u, ALPHA * u);
            v[s] = u;
            mx = fmaxf(mx, u);
        }
        const unsigned int mu = (unsigned int)f2bf(mx);
        const float mUse = __uint_as_float(mu << 16);
        float sum = 0.f;
#pragma unroll
        for (int s = 0; s < SS; ++s)
            sum += exp2f(v[s] - mUse);
        const int i = i0 + ii;
        const int adj = Adj[(size_t)i * NN + t];
        const float r = (adj > 0) ? (1.f / sum) : -0.015625f;
        MRw[((((size_t)b * 16 + (i >> 4)) * 32 + (t >> 3)) * 16 + (i & 15)) * 8
            + (t & 7)] = (mu << 16) | (unsigned int)f2bf(r);
    }
}

// ------ Kernel 3b: O = ELU(A @ H) via bf16 MFMA. 256 thr, 1024 blocks --------
// Block = (b XCD-pinned, s, row-half). 4 waves x 32 rows. ks-split chunk loop
// keeps VGPR <= 128 (launch_bounds min-waves 4 => 4 blocks/CU).
__global__ __launch_bounds__(256, 4) void k_attn(
    const ushort_t* __restrict__ HbTw, const float* __restrict__ E1,
    const float* __restrict__ E2, const unsigned int* __restrict__ MRw,
    float* __restrict__ out)
{
    const int b = blockIdx.x & 7;            // XCD-pinned batch
    const int k2 = blockIdx.x >> 3;          // 0..127
    const int s = k2 >> 1;
    const int half = k2 & 1;
    const int bs = b * 64 + s;
    const int tid = threadIdx.x;
    const int wid = tid >> 6;                // wave 0..3
    const int lane = tid & 63;
    const int l15 = lane & 15;
    const int lhi = lane >> 4;
    const int rb0 = half * 128 + wid * 32;   // this wave's first output row

    __shared__ float e2s[NN];
    e2s[tid] = E2[(size_t)bs * NN + tid];
    __syncthreads();

    float e1r[2];
#pragma unroll
    for (int mt = 0; mt < 2; ++mt)
        e1r[mt] = E1[(size_t)bs * NN + rb0 + mt * 16 + l15];

    f32x4 acc[2][4];
#pragma unroll
    for (int mt = 0; mt < 2; ++mt)
#pragma unroll
        for (int nt = 0; nt < 4; ++nt) acc[mt][nt] = (f32x4){0.f, 0.f, 0.f, 0.f};

    const ushort_t* hbw = HbTw + (size_t)bs * (OF * NN);
    const unsigned int* mrb = MRw + (size_t)b * (NN * NN);
    const unsigned int* mr0 = mrb + ((size_t)((rb0 >> 4) + 0) * 32) * 128 + l15 * 8;
    const unsigned int* mr1 = mrb + ((size_t)((rb0 >> 4) + 1) * 32) * 128 + l15 * 8;

    for (int ch = 0; ch < 4; ++ch) {
#pragma unroll
        for (int ks = 0; ks < 2; ++ks) {
            const int kb = ch * 8 + ks * 4 + lhi;   // j/8 block index
            // B fragments: contiguous 16B/lane
            short8 bfr[4];
#pragma unroll
            for (int nt = 0; nt < 4; ++nt)
                bfr[nt] = *(const short8*)(hbw + ((size_t)(nt * 32 + kb) * 16 + l15) * 8);
            // MR stats: contiguous 32B/lane per mt
            uint4 mq[2][2];
            mq[0][0] = *(const uint4*)(mr0 + kb * 128);
            mq[0][1] = *(const uint4*)(mr0 + kb * 128 + 4);
            mq[1][0] = *(const uint4*)(mr1 + kb * 128);
            mq[1][1] = *(const uint4*)(mr1 + kb * 128 + 4);
            // e2 slice
            const int k0 = ch * 64 + ks * 32 + lhi * 8;
            const float4 lo = *(const float4*)&e2s[k0];
            const float4 hi = *(const float4*)&e2s[k0 + 4];
            const float e2v[8] = {lo.x, lo.y, lo.z, lo.w, hi.x, hi.y, hi.z, hi.w};
            // A fragments + MFMA
#pragma unroll
            for (int mt = 0; mt < 2; ++mt) {
                const float e1v = e1r[mt];
                const unsigned int wv[8] = {
                    mq[mt][0].x, mq[mt][0].y, mq[mt][0].z, mq[mt][0].w,
                    mq[mt][1].x, mq[mt][1].y, mq[mt][1].z, mq[mt][1].w};
                short8 pk;
#pragma unroll
                for (int kk = 0; kk < 8; ++kk) {
                    const float Mf = __uint_as_float(wv[kk] & 0xFFFF0000u);
                    const float Rf = __uint_as_float(wv[kk] << 16);
                    float v = e1v + e2v[kk];
                    v = fmaxf(v, ALPHA * v);
                    const float a = (Rf < 0.f) ? -Rf : exp2f(v - Mf) * Rf;
                    pk[kk] = (short)f2bf(a);
                }
#pragma unroll
                for (int nt = 0; nt < 4; ++nt)
                    acc[mt][nt] = __builtin_amdgcn_mfma_f32_16x16x32_bf16(
                        pk, bfr[nt], acc[mt][nt], 0, 0, 0);
            }
        }
    }

    // ---- epilogue: ELU + store f32
    float* ob = out + (size_t)bs * (NN * OF);
#pragma unroll
    for (int mt = 0; mt < 2; ++mt) {
        const int rbase = rb0 + mt * 16 + lhi * 4;
#pragma unroll
        for (int nt = 0; nt < 4; ++nt) {
            const int o = nt * 16 + l15;
#pragma unroll
            for (int reg = 0; reg < 4; ++reg) {
                float v = acc[mt][nt][reg];
                v = (v > 0.f) ? v : (__expf(v) - 1.f);
                ob[(size_t)(rbase + reg) * OF + o] = v;
            }
        }
    }
}

extern "C" void kernel_launch(void* const* d_in, const int* in_sizes, int n_in,
                              void* d_out, int out_size, void* d_ws, size_t ws_size,
                              hipStream_t stream)
{
    const float* hyper = (const float*)d_in[0];
    const float* x     = (const float*)d_in[1];
    const int*   Adj   = (const int*)d_in[2];
    const float* w1    = (const float*)d_in[3];
    const float* b1    = (const float*)d_in[4];
    const float* w2    = (const float*)d_in[5];
    const float* b2    = (const float*)d_in[6];
    const float* aw1   = (const float*)d_in[7];
    const float* ab1   = (const float*)d_in[8];
    const float* aw2   = (const float*)d_in[9];
    const float* ab2   = (const float*)d_in[10];
    float* out = (float*)d_out;

    float* ws      = (float*)d_ws;
    float* Wd      = ws;                      // 512*4096
    float* Aa      = Wd + 2097152;            // 512*128
    ushort_t* HbTw = (ushort_t*)(Aa + 65536); // 512*64*256 bf16, fragment-native
    float* E1      = (float*)(HbTw + 8388608);// 512*256 (log2e-scaled)
    float* E2      = E1 + 131072;             // 512*256 (log2e-scaled)
    unsigned int* MRw = (unsigned int*)(E2 + 131072); // 8*256*256, fragment-native

    k_hyper2<<<dim3(256), dim3(512), 0, stream>>>(hyper, w1, b1, w2, b2,
                                                  aw1, ab1, aw2, ab2, Wd, Aa);
    k_h<<<dim3(512), dim3(256), 0, stream>>>(x, Wd, Aa, HbTw, E1, E2);
    k_softstats<<<dim3(512), dim3(256), 0, stream>>>(E1, E2, Adj, MRw);
    k_attn<<<dim3(1024), dim3(256), 0, stream>>>(HbTw, E1, E2, MRw, out);
}